// Round 1
// baseline (139.710 us; speedup 1.0000x reference)
//
#include <hip/hip_runtime.h>

// SSIM loss via MFMA band-matrix convolutions (gfx950).
//   H-pass: D(16x16) = A(16 rows x 32-col window, f16 from global) x Bband(32x16)
//           Bband[k][n] = W[k-n-3]; 5 fields share A loads (x,y,x2,y2,xy).
//           D stored transposed to LDS hf_t[field][col][hf_row] (b64/lane).
//   V-pass: D(16x16) = Aband(16x32) x B(hf_t frag, b128/lane)
//           Aband[m][k] = W[k-m]; f32 accum -> packed-f32 SSIM -> reduce.
// R9: 16x128 tile (no col-tile overlap, LDS 23.75 KB -> 6 blocks/CU),
//     v_pk_*_f32 epilogue, balanced P3 (2 groups/wave).
// R10 (this round): unchanged resubmit — prior bench infra-failed
//     (GPUAcquisitionTimeout); need baseline counters before editing.

namespace {
constexpr int IMG   = 512;
constexpr int NCH   = 48;              // 16 * 3
constexpr int TW    = 16;              // tile cols
constexpr int TH    = 128;             // tile rows
constexpr int RSTR  = 152;             // hf_t row-dim stride (f16 units, mult of 8)
constexpr int TPX   = IMG / TW;        // 32
constexpr int TPY   = IMG / TH;        // 4
constexpr int NBLK  = TPX * TPY * NCH; // 6144
constexpr int FB    = NBLK / 256;      // 24

constexpr float Wf[11] = {
    0.00102838f, 0.00759876f, 0.03600077f, 0.10936069f, 0.21300554f,
    0.26601172f,
    0.21300554f, 0.10936069f, 0.03600077f, 0.00759876f, 0.00102838f };
}

typedef _Float16 half8 __attribute__((ext_vector_type(8)));
typedef _Float16 half4v __attribute__((ext_vector_type(4)));
typedef _Float16 h2 __attribute__((ext_vector_type(2)));
typedef float float4v __attribute__((ext_vector_type(4)));
typedef float float2v __attribute__((ext_vector_type(2)));

__device__ inline float band_w(int d) {   // W[d] for d in [0,11), else 0
    float v = 0.f;
    #pragma unroll
    for (int k = 0; k < 11; ++k) v = (d == k) ? Wf[k] : v;
    return v;
}

__device__ inline h2 pk(float a, float b) {
    auto v = __builtin_amdgcn_cvt_pkrtz(a, b);
    h2 r;
    __builtin_memcpy(&r, &v, sizeof(r));
    return r;
}

union H8 { half8 v; h2 p[4]; };

__global__ __launch_bounds__(256, 6) void ssim_tile_kernel(
    const float* __restrict__ pred, const float* __restrict__ tgt,
    float* __restrict__ partial)
{
    __shared__ __align__(16) _Float16 hf_t[5][TW][RSTR];   // 23.75 KB
    __shared__ float wred[4];

    const int t    = threadIdx.x;
    const int w    = t >> 6;              // wave 0..3
    const int lane = t & 63;
    const int nr   = lane & 15;
    const int quad = lane >> 4;

    const int bid  = blockIdx.x;
    const int img  = bid >> 7;            // 128 tiles per plane
    const int tile = bid & 127;
    const int txi  = tile >> 2;           // 0..31 (horiz neighbors +-4 bid)
    const int tyi  = tile & 3;            // 0..3
    const int tx   = txi * TW;
    const int ty   = tyi * TH;

    const float* __restrict__ p = pred + (size_t)img * (IMG * IMG);
    const float* __restrict__ q = tgt  + (size_t)img * (IMG * IMG);

    // ---- constant band fragments (select chains fold to immediates) ----
    half8 Aband, Bband;    // Aband[jj]=W[k-m] (V-pass A), Bband[jj]=W[k-n-3] (H-pass B)
    #pragma unroll
    for (int jj = 0; jj < 8; ++jj) {
        int k = quad * 8 + jj;
        Aband[jj] = (_Float16)band_w(k - nr);
        Bband[jj] = (_Float16)band_w(k - nr - 3);
    }
    const float4v zf = {0.f, 0.f, 0.f, 0.f};
    const half8 z8 = {};

    // ===== P2: horizontal conv via MFMA, global -> hf_t (9 stripes) =====
    for (int s = w; s < 9; s += 4) {
        const int gy  = ty + 16 * s + nr - 5;
        const int gyc = min(max(gy, 0), IMG - 1);
        const int cb  = tx - 8 + (quad << 3);      // frag col base (mult of 8)
        const int cbc = min(max(cb, 0), IMG - 8);
        const bool ok = ((unsigned)gy < (unsigned)IMG) &&
                        ((unsigned)cb <= (unsigned)(IMG - 8));
        const float* rp = p + gyc * IMG + cbc;
        const float* rq = q + gyc * IMG + cbc;
        float4 xa = *(const float4*)rp;
        float4 xb = *(const float4*)(rp + 4);
        float4 ya = *(const float4*)rq;
        float4 yb = *(const float4*)(rq + 4);

        H8 ax, ay;
        ax.p[0] = pk(xa.x, xa.y); ax.p[1] = pk(xa.z, xa.w);
        ax.p[2] = pk(xb.x, xb.y); ax.p[3] = pk(xb.z, xb.w);
        ay.p[0] = pk(ya.x, ya.y); ay.p[1] = pk(ya.z, ya.w);
        ay.p[2] = pk(yb.x, yb.y); ay.p[3] = pk(yb.z, yb.w);
        if (!ok) { ax.v = z8; ay.v = z8; }

        half8 fx  = ax.v;
        half8 fy  = ay.v;
        half8 fxx = fx * fx;
        half8 fyy = fy * fy;
        half8 fxy = fx * fy;

        float4v D[5];
        D[0] = __builtin_amdgcn_mfma_f32_16x16x32_f16(fx,  Bband, zf, 0, 0, 0);
        D[1] = __builtin_amdgcn_mfma_f32_16x16x32_f16(fy,  Bband, zf, 0, 0, 0);
        D[2] = __builtin_amdgcn_mfma_f32_16x16x32_f16(fxx, Bband, zf, 0, 0, 0);
        D[3] = __builtin_amdgcn_mfma_f32_16x16x32_f16(fyy, Bband, zf, 0, 0, 0);
        D[4] = __builtin_amdgcn_mfma_f32_16x16x32_f16(fxy, Bband, zf, 0, 0, 0);

        // D: col n = nr, rows m = quad*4+reg -> hf_t[f][n][16s+4q+reg] (b64)
        const int r0 = 16 * s + (quad << 2);
        #pragma unroll
        for (int f = 0; f < 5; ++f) {
            h2 lo = pk(D[f][0], D[f][1]);
            h2 hi = pk(D[f][2], D[f][3]);
            half4v hh = {lo[0], lo[1], hi[0], hi[1]};
            *(half4v*)&hf_t[f][nr][r0] = hh;
        }
    }
    __syncthreads();

    // ===== P3: vertical conv via MFMA + packed-f32 SSIM epilogue =====
    constexpr float C1 = 1e-4f, C2 = 9e-4f;
    const float2v C1v = {C1, C1};
    const float2v C2v = {C2, C2};
    const float2v K12 = {C1 + C2, C1 + C2};
    float2v lsum2 = {0.f, 0.f};
    for (int s = w; s < 8; s += 4) {
        const int rb = 16 * s + (quad << 3);
        float4v acc[5];
        #pragma unroll
        for (int f = 0; f < 5; ++f) {
            half8 bf = *(const half8*)&hf_t[f][nr][rb];   // b128
            acc[f] = __builtin_amdgcn_mfma_f32_16x16x32_f16(Aband, bf, zf, 0, 0, 0);
        }
        #pragma unroll
        for (int h = 0; h < 2; ++h) {
            float2v mx  = {acc[0][2*h], acc[0][2*h+1]};
            float2v my  = {acc[1][2*h], acc[1][2*h+1]};
            float2v ex2 = {acc[2][2*h], acc[2][2*h+1]};
            float2v ey2 = {acc[3][2*h], acc[3][2*h+1]};
            float2v exy = {acc[4][2*h], acc[4][2*h+1]};
            float2v P  = mx * my;
            float2v U  = mx * mx + my * my + C1v;     // mus^2 sum + C1
            float2v n1 = 2.f * P + C1v;
            float2v n2 = 2.f * (exy - P) + C2v;
            float2v num = n1 * n2;
            float2v e1 = (ex2 + ey2) - U + K12;       // sgx+sgy+C2
            float2v den = U * e1;
            float2v r = {__builtin_amdgcn_rcpf(den.x),
                         __builtin_amdgcn_rcpf(den.y)};
            lsum2 += num * r;
        }
    }
    float lsum = lsum2.x + lsum2.y;

    #pragma unroll
    for (int off = 32; off > 0; off >>= 1)
        lsum += __shfl_down(lsum, off, 64);
    if (lane == 0) wred[w] = lsum;
    __syncthreads();
    if (t == 0) partial[bid] = wred[0] + wred[1] + wred[2] + wred[3];
}

__global__ __launch_bounds__(256) void ssim_finishA(float* __restrict__ partial)
{
    __shared__ float wred[4];
    const int t = threadIdx.x;
    float s = partial[blockIdx.x * 256 + t];
    #pragma unroll
    for (int off = 32; off > 0; off >>= 1)
        s += __shfl_down(s, off, 64);
    if ((t & 63) == 0) wred[t >> 6] = s;
    __syncthreads();
    if (t == 0) partial[blockIdx.x * 256] = wred[0] + wred[1] + wred[2] + wred[3];
}

__global__ __launch_bounds__(64) void ssim_finishB(
    const float* __restrict__ partial, float* __restrict__ out)
{
    const int t = threadIdx.x;
    float s = (t < FB) ? partial[t * 256] : 0.f;
    #pragma unroll
    for (int off = 32; off > 0; off >>= 1)
        s += __shfl_down(s, off, 64);
    if (t == 0)
        out[0] = 1.f - s * (1.f / (float)((long long)NCH * IMG * IMG));
}

extern "C" void kernel_launch(void* const* d_in, const int* in_sizes, int n_in,
                              void* d_out, int out_size, void* d_ws, size_t ws_size,
                              hipStream_t stream)
{
    const float* pred = (const float*)d_in[0];
    const float* tgt  = (const float*)d_in[1];
    float* out     = (float*)d_out;
    float* partial = (float*)d_ws;    // NBLK floats = 24 KB

    ssim_tile_kernel<<<NBLK, 256, 0, stream>>>(pred, tgt, partial);
    ssim_finishA<<<FB, 256, 0, stream>>>(partial);
    ssim_finishB<<<1, 64, 0, stream>>>(partial, out);
}

// Round 4
// 135.546 us; speedup vs baseline: 1.0307x; 1.0307x over previous
//
#include <hip/hip_runtime.h>

// SSIM loss via MFMA band-matrix convolutions (gfx950).
//   H-pass: D(16x16) = A(16 rows x 32-col window, f16 from global) x Bband(32x16)
//   V-pass: D(16x16) = Aband(16x32) x B(hf_t frag, b128/lane)
// R9: 16x128 tile, LDS 23.75 KB -> 6 blocks/CU, packed-f32 epilogue.
// R11: (a) software-pipelined P2 (2-deep stripe load pipeline);
//      (b) finishA+finishB merged into ONE single-block kernel.
// R13 (this round): unchanged resubmit — R11/R12 benches infra-failed
//     (GPUAcquisitionTimeout x2); the pipelined kernel has not been measured.

namespace {
constexpr int IMG   = 512;
constexpr int NCH   = 48;              // 16 * 3
constexpr int TW    = 16;              // tile cols
constexpr int TH    = 128;             // tile rows
constexpr int RSTR  = 152;             // hf_t row-dim stride (f16 units, mult of 8)
constexpr int TPX   = IMG / TW;        // 32
constexpr int TPY   = IMG / TH;        // 4
constexpr int NBLK  = TPX * TPY * NCH; // 6144

constexpr float Wf[11] = {
    0.00102838f, 0.00759876f, 0.03600077f, 0.10936069f, 0.21300554f,
    0.26601172f,
    0.21300554f, 0.10936069f, 0.03600077f, 0.00759876f, 0.00102838f };
}

typedef _Float16 half8 __attribute__((ext_vector_type(8)));
typedef _Float16 half4v __attribute__((ext_vector_type(4)));
typedef _Float16 h2 __attribute__((ext_vector_type(2)));
typedef float float4v __attribute__((ext_vector_type(4)));
typedef float float2v __attribute__((ext_vector_type(2)));

__device__ inline float band_w(int d) {   // W[d] for d in [0,11), else 0
    float v = 0.f;
    #pragma unroll
    for (int k = 0; k < 11; ++k) v = (d == k) ? Wf[k] : v;
    return v;
}

__device__ inline h2 pk(float a, float b) {
    auto v = __builtin_amdgcn_cvt_pkrtz(a, b);
    h2 r;
    __builtin_memcpy(&r, &v, sizeof(r));
    return r;
}

union H8 { half8 v; h2 p[4]; };

__global__ __launch_bounds__(256, 6) void ssim_tile_kernel(
    const float* __restrict__ pred, const float* __restrict__ tgt,
    float* __restrict__ partial)
{
    __shared__ __align__(16) _Float16 hf_t[5][TW][RSTR];   // 23.75 KB
    __shared__ float wred[4];

    const int t    = threadIdx.x;
    const int w    = t >> 6;              // wave 0..3
    const int lane = t & 63;
    const int nr   = lane & 15;
    const int quad = lane >> 4;

    const int bid  = blockIdx.x;
    const int img  = bid >> 7;            // 128 tiles per plane
    const int tile = bid & 127;
    const int txi  = tile >> 2;           // 0..31 (horiz neighbors +-4 bid)
    const int tyi  = tile & 3;            // 0..3
    const int tx   = txi * TW;
    const int ty   = tyi * TH;

    const float* __restrict__ p = pred + (size_t)img * (IMG * IMG);
    const float* __restrict__ q = tgt  + (size_t)img * (IMG * IMG);

    // ---- constant band fragments (select chains fold to immediates) ----
    half8 Aband, Bband;    // Aband[jj]=W[k-m] (V-pass A), Bband[jj]=W[k-n-3] (H-pass B)
    #pragma unroll
    for (int jj = 0; jj < 8; ++jj) {
        int k = quad * 8 + jj;
        Aband[jj] = (_Float16)band_w(k - nr);
        Bband[jj] = (_Float16)band_w(k - nr - 3);
    }
    const float4v zf = {0.f, 0.f, 0.f, 0.f};
    const half8 z8 = {};

    // column base shared by all stripes of this thread
    const int cb  = tx - 8 + (quad << 3);      // frag col base (mult of 8)
    const int cbc = min(max(cb, 0), IMG - 8);
    const bool okc = ((unsigned)cb <= (unsigned)(IMG - 8));

    // ---- stripe load: 4 x global_load_dwordx4 (clamped addresses) ----
    auto ld_stripe = [&](int s, float4& xa, float4& xb, float4& ya, float4& yb) {
        const int gy  = ty + 16 * s + nr - 5;
        const int gyc = min(max(gy, 0), IMG - 1);
        const float* rp = p + gyc * IMG + cbc;
        const float* rq = q + gyc * IMG + cbc;
        xa = *(const float4*)rp;
        xb = *(const float4*)(rp + 4);
        ya = *(const float4*)rq;
        yb = *(const float4*)(rq + 4);
    };

    // ---- stripe process: cvt -> products -> 5 MFMA -> LDS (transposed) ----
    auto proc_stripe = [&](int s, float4 xa, float4 xb, float4 ya, float4 yb) {
        const int gy = ty + 16 * s + nr - 5;
        const bool ok = ((unsigned)gy < (unsigned)IMG) && okc;

        H8 ax, ay;
        ax.p[0] = pk(xa.x, xa.y); ax.p[1] = pk(xa.z, xa.w);
        ax.p[2] = pk(xb.x, xb.y); ax.p[3] = pk(xb.z, xb.w);
        ay.p[0] = pk(ya.x, ya.y); ay.p[1] = pk(ya.z, ya.w);
        ay.p[2] = pk(yb.x, yb.y); ay.p[3] = pk(yb.z, yb.w);
        if (!ok) { ax.v = z8; ay.v = z8; }

        half8 fx  = ax.v;
        half8 fy  = ay.v;
        half8 fxx = fx * fx;
        half8 fyy = fy * fy;
        half8 fxy = fx * fy;

        float4v D[5];
        D[0] = __builtin_amdgcn_mfma_f32_16x16x32_f16(fx,  Bband, zf, 0, 0, 0);
        D[1] = __builtin_amdgcn_mfma_f32_16x16x32_f16(fy,  Bband, zf, 0, 0, 0);
        D[2] = __builtin_amdgcn_mfma_f32_16x16x32_f16(fxx, Bband, zf, 0, 0, 0);
        D[3] = __builtin_amdgcn_mfma_f32_16x16x32_f16(fyy, Bband, zf, 0, 0, 0);
        D[4] = __builtin_amdgcn_mfma_f32_16x16x32_f16(fxy, Bband, zf, 0, 0, 0);

        // D: col n = nr, rows m = quad*4+reg -> hf_t[f][n][16s+4q+reg] (b64)
        const int r0 = 16 * s + (quad << 2);
        #pragma unroll
        for (int f = 0; f < 5; ++f) {
            h2 lo = pk(D[f][0], D[f][1]);
            h2 hi = pk(D[f][2], D[f][3]);
            half4v hh = {lo[0], lo[1], hi[0], hi[1]};
            *(half4v*)&hf_t[f][nr][r0] = hh;
        }
    };

    // ===== P2: 9 stripes over 4 waves, 2-deep load pipeline =====
    // wave w handles stripes {w, w+4} and wave 0 additionally stripe 8.
    {
        float4 xa0, xb0, ya0, yb0, xa1, xb1, ya1, yb1;
        ld_stripe(w,     xa0, xb0, ya0, yb0);      // in flight
        ld_stripe(w + 4, xa1, xb1, ya1, yb1);      // in flight
        proc_stripe(w, xa0, xb0, ya0, yb0);
        if (w == 0) {
            float4 xa2, xb2, ya2, yb2;
            ld_stripe(8, xa2, xb2, ya2, yb2);      // overlaps proc of stripe 4
            proc_stripe(4, xa1, xb1, ya1, yb1);
            proc_stripe(8, xa2, xb2, ya2, yb2);
        } else {
            proc_stripe(w + 4, xa1, xb1, ya1, yb1);
        }
    }
    __syncthreads();

    // ===== P3: vertical conv via MFMA + packed-f32 SSIM epilogue =====
    constexpr float C1 = 1e-4f, C2 = 9e-4f;
    const float2v C1v = {C1, C1};
    const float2v C2v = {C2, C2};
    const float2v K12 = {C1 + C2, C1 + C2};
    float2v lsum2 = {0.f, 0.f};
    for (int s = w; s < 8; s += 4) {
        const int rb = 16 * s + (quad << 3);
        float4v acc[5];
        #pragma unroll
        for (int f = 0; f < 5; ++f) {
            half8 bf = *(const half8*)&hf_t[f][nr][rb];   // b128
            acc[f] = __builtin_amdgcn_mfma_f32_16x16x32_f16(Aband, bf, zf, 0, 0, 0);
        }
        #pragma unroll
        for (int h = 0; h < 2; ++h) {
            float2v mx  = {acc[0][2*h], acc[0][2*h+1]};
            float2v my  = {acc[1][2*h], acc[1][2*h+1]};
            float2v ex2 = {acc[2][2*h], acc[2][2*h+1]};
            float2v ey2 = {acc[3][2*h], acc[3][2*h+1]};
            float2v exy = {acc[4][2*h], acc[4][2*h+1]};
            float2v P  = mx * my;
            float2v U  = mx * mx + my * my + C1v;     // mus^2 sum + C1
            float2v n1 = 2.f * P + C1v;
            float2v n2 = 2.f * (exy - P) + C2v;
            float2v num = n1 * n2;
            float2v e1 = (ex2 + ey2) - U + K12;       // sgx+sgy+C2
            float2v den = U * e1;
            float2v r = {__builtin_amdgcn_rcpf(den.x),
                         __builtin_amdgcn_rcpf(den.y)};
            lsum2 += num * r;
        }
    }
    float lsum = lsum2.x + lsum2.y;

    #pragma unroll
    for (int off = 32; off > 0; off >>= 1)
        lsum += __shfl_down(lsum, off, 64);
    if (lane == 0) wred[w] = lsum;
    __syncthreads();
    if (t == 0) partial[bid] = wred[0] + wred[1] + wred[2] + wred[3];
}

// Single-block finish: 1024 threads x 6 loads, deterministic tree reduce.
__global__ __launch_bounds__(1024) void ssim_finish(
    const float* __restrict__ partial, float* __restrict__ out)
{
    __shared__ float wred[16];
    const int t = threadIdx.x;
    float s = 0.f;
    #pragma unroll
    for (int i = 0; i < NBLK / 1024; ++i)
        s += partial[t + i * 1024];
    #pragma unroll
    for (int off = 32; off > 0; off >>= 1)
        s += __shfl_down(s, off, 64);
    if ((t & 63) == 0) wred[t >> 6] = s;
    __syncthreads();
    if (t == 0) {
        float acc = 0.f;
        #pragma unroll
        for (int i = 0; i < 16; ++i) acc += wred[i];
        out[0] = 1.f - acc * (1.f / (float)((long long)NCH * IMG * IMG));
    }
}

extern "C" void kernel_launch(void* const* d_in, const int* in_sizes, int n_in,
                              void* d_out, int out_size, void* d_ws, size_t ws_size,
                              hipStream_t stream)
{
    const float* pred = (const float*)d_in[0];
    const float* tgt  = (const float*)d_in[1];
    float* out     = (float*)d_out;
    float* partial = (float*)d_ws;    // NBLK floats = 24 KB

    ssim_tile_kernel<<<NBLK, 256, 0, stream>>>(pred, tgt, partial);
    ssim_finish<<<1, 1024, 0, stream>>>(partial, out);
}

// Round 5
// 134.687 us; speedup vs baseline: 1.0373x; 1.0064x over previous
//
#include <hip/hip_runtime.h>

// SSIM loss via MFMA band-matrix convolutions (gfx950).
//   H-pass: D(16x16) = A(16 rows x 32-col window, f16 from global) x Bband(32x16)
//   V-pass: D(16x16) = Aband(16x32) x B(hf_t frag, b128/lane)
// R9: 16x128 tile, LDS 23.75 KB -> 6 blocks/CU, packed-f32 epilogue.
// R11: pipelined P2 (measured neutral: compiler re-sinks loads; VGPR stayed 40)
//      + merged finish kernel (real win, ~-3 us launch overhead).
// R14 (this round): band fragments from a compile-time __constant__ table.
//   R11 post-mortem: VALUBusy 50% vs ~6% static estimate of the real work.
//   band_w(k - nr) is LANE-DEPENDENT -> ~350 v_cmp/v_cndmask per thread per
//   block (the "folds to immediates" comment was wrong). Replace with two
//   16B table loads. Predict VALUBusy -> ~35%, tile 48.8 -> ~42 us.

namespace {
constexpr int IMG   = 512;
constexpr int NCH   = 48;              // 16 * 3
constexpr int TW    = 16;              // tile cols
constexpr int TH    = 128;             // tile rows
constexpr int RSTR  = 152;             // hf_t row-dim stride (f16 units, mult of 8)
constexpr int TPX   = IMG / TW;        // 32
constexpr int TPY   = IMG / TH;        // 4
constexpr int NBLK  = TPX * TPY * NCH; // 6144

constexpr float Wf[11] = {
    0.00102838f, 0.00759876f, 0.03600077f, 0.10936069f, 0.21300554f,
    0.26601172f,
    0.21300554f, 0.10936069f, 0.03600077f, 0.00759876f, 0.00102838f };

constexpr float band_wc(int d) {       // W[d] for d in [0,11), else 0
    return (d >= 0 && d < 11) ? Wf[d] : 0.f;
}

// constexpr f32 -> f16 bits, round-to-nearest-even (inputs are 0 or positive
// normal-range values; matches runtime (_Float16) cast bit-exactly).
constexpr unsigned short f2h(float f) {
    if (f == 0.f) return 0;
    unsigned u = __builtin_bit_cast(unsigned, f);
    int  he = int((u >> 23) & 0xff) - 127 + 15;   // our values: he in [5,15]
    unsigned hm   = (u & 0x7fffff) >> 13;
    unsigned rest = u & 0x1fff;
    if (rest > 0x1000 || (rest == 0x1000 && (hm & 1))) ++hm;
    return (unsigned short)((unsigned(he) << 10) + hm);   // carry ok
}

struct Tabs { unsigned short a[64][8]; unsigned short b[64][8]; };
constexpr Tabs build_tabs() {
    Tabs t{};
    for (int lane = 0; lane < 64; ++lane) {
        const int nr = lane & 15, quad = lane >> 4;
        for (int jj = 0; jj < 8; ++jj) {
            const int k = quad * 8 + jj;
            t.a[lane][jj] = f2h(band_wc(k - nr));       // V-pass A: W[k-m]
            t.b[lane][jj] = f2h(band_wc(k - nr - 3));   // H-pass B: W[k-n-3]
        }
    }
    return t;
}
}

__device__ __constant__ __align__(16) Tabs g_tabs = build_tabs();

typedef _Float16 half8 __attribute__((ext_vector_type(8)));
typedef _Float16 half4v __attribute__((ext_vector_type(4)));
typedef _Float16 h2 __attribute__((ext_vector_type(2)));
typedef float float4v __attribute__((ext_vector_type(4)));
typedef float float2v __attribute__((ext_vector_type(2)));

__device__ inline h2 pk(float a, float b) {
    auto v = __builtin_amdgcn_cvt_pkrtz(a, b);
    h2 r;
    __builtin_memcpy(&r, &v, sizeof(r));
    return r;
}

union H8 { half8 v; h2 p[4]; };

__global__ __launch_bounds__(256, 6) void ssim_tile_kernel(
    const float* __restrict__ pred, const float* __restrict__ tgt,
    float* __restrict__ partial)
{
    __shared__ __align__(16) _Float16 hf_t[5][TW][RSTR];   // 23.75 KB
    __shared__ float wred[4];

    const int t    = threadIdx.x;
    const int w    = t >> 6;              // wave 0..3
    const int lane = t & 63;
    const int nr   = lane & 15;
    const int quad = lane >> 4;

    const int bid  = blockIdx.x;
    const int img  = bid >> 7;            // 128 tiles per plane
    const int tile = bid & 127;
    const int txi  = tile >> 2;           // 0..31 (horiz neighbors +-4 bid)
    const int tyi  = tile & 3;            // 0..3
    const int tx   = txi * TW;
    const int ty   = tyi * TH;

    const float* __restrict__ p = pred + (size_t)img * (IMG * IMG);
    const float* __restrict__ q = tgt  + (size_t)img * (IMG * IMG);

    // ---- band fragments: two 16B loads from the compile-time table ----
    const half8 Aband = *(const half8*)(g_tabs.a[lane]);
    const half8 Bband = *(const half8*)(g_tabs.b[lane]);
    const float4v zf = {0.f, 0.f, 0.f, 0.f};
    const half8 z8 = {};

    // column base shared by all stripes of this thread
    const int cb  = tx - 8 + (quad << 3);      // frag col base (mult of 8)
    const int cbc = min(max(cb, 0), IMG - 8);
    const bool okc = ((unsigned)cb <= (unsigned)(IMG - 8));

    // ---- stripe load: 4 x global_load_dwordx4 (clamped addresses) ----
    auto ld_stripe = [&](int s, float4& xa, float4& xb, float4& ya, float4& yb) {
        const int gy  = ty + 16 * s + nr - 5;
        const int gyc = min(max(gy, 0), IMG - 1);
        const float* rp = p + gyc * IMG + cbc;
        const float* rq = q + gyc * IMG + cbc;
        xa = *(const float4*)rp;
        xb = *(const float4*)(rp + 4);
        ya = *(const float4*)rq;
        yb = *(const float4*)(rq + 4);
    };

    // ---- stripe process: cvt -> products -> 5 MFMA -> LDS (transposed) ----
    auto proc_stripe = [&](int s, float4 xa, float4 xb, float4 ya, float4 yb) {
        const int gy = ty + 16 * s + nr - 5;
        const bool ok = ((unsigned)gy < (unsigned)IMG) && okc;

        H8 ax, ay;
        ax.p[0] = pk(xa.x, xa.y); ax.p[1] = pk(xa.z, xa.w);
        ax.p[2] = pk(xb.x, xb.y); ax.p[3] = pk(xb.z, xb.w);
        ay.p[0] = pk(ya.x, ya.y); ay.p[1] = pk(ya.z, ya.w);
        ay.p[2] = pk(yb.x, yb.y); ay.p[3] = pk(yb.z, yb.w);
        if (!ok) { ax.v = z8; ay.v = z8; }

        half8 fx  = ax.v;
        half8 fy  = ay.v;
        half8 fxx = fx * fx;
        half8 fyy = fy * fy;
        half8 fxy = fx * fy;

        float4v D[5];
        D[0] = __builtin_amdgcn_mfma_f32_16x16x32_f16(fx,  Bband, zf, 0, 0, 0);
        D[1] = __builtin_amdgcn_mfma_f32_16x16x32_f16(fy,  Bband, zf, 0, 0, 0);
        D[2] = __builtin_amdgcn_mfma_f32_16x16x32_f16(fxx, Bband, zf, 0, 0, 0);
        D[3] = __builtin_amdgcn_mfma_f32_16x16x32_f16(fyy, Bband, zf, 0, 0, 0);
        D[4] = __builtin_amdgcn_mfma_f32_16x16x32_f16(fxy, Bband, zf, 0, 0, 0);

        // D: col n = nr, rows m = quad*4+reg -> hf_t[f][n][16s+4q+reg] (b64)
        const int r0 = 16 * s + (quad << 2);
        #pragma unroll
        for (int f = 0; f < 5; ++f) {
            h2 lo = pk(D[f][0], D[f][1]);
            h2 hi = pk(D[f][2], D[f][3]);
            half4v hh = {lo[0], lo[1], hi[0], hi[1]};
            *(half4v*)&hf_t[f][nr][r0] = hh;
        }
    };

    // ===== P2: 9 stripes over 4 waves =====
    // wave w handles stripes {w, w+4} and wave 0 additionally stripe 8.
    {
        float4 xa0, xb0, ya0, yb0, xa1, xb1, ya1, yb1;
        ld_stripe(w,     xa0, xb0, ya0, yb0);
        ld_stripe(w + 4, xa1, xb1, ya1, yb1);
        proc_stripe(w, xa0, xb0, ya0, yb0);
        if (w == 0) {
            float4 xa2, xb2, ya2, yb2;
            ld_stripe(8, xa2, xb2, ya2, yb2);
            proc_stripe(4, xa1, xb1, ya1, yb1);
            proc_stripe(8, xa2, xb2, ya2, yb2);
        } else {
            proc_stripe(w + 4, xa1, xb1, ya1, yb1);
        }
    }
    __syncthreads();

    // ===== P3: vertical conv via MFMA + packed-f32 SSIM epilogue =====
    constexpr float C1 = 1e-4f, C2 = 9e-4f;
    const float2v C1v = {C1, C1};
    const float2v C2v = {C2, C2};
    const float2v K12 = {C1 + C2, C1 + C2};
    float2v lsum2 = {0.f, 0.f};
    for (int s = w; s < 8; s += 4) {
        const int rb = 16 * s + (quad << 3);
        float4v acc[5];
        #pragma unroll
        for (int f = 0; f < 5; ++f) {
            half8 bf = *(const half8*)&hf_t[f][nr][rb];   // b128
            acc[f] = __builtin_amdgcn_mfma_f32_16x16x32_f16(Aband, bf, zf, 0, 0, 0);
        }
        #pragma unroll
        for (int h = 0; h < 2; ++h) {
            float2v mx  = {acc[0][2*h], acc[0][2*h+1]};
            float2v my  = {acc[1][2*h], acc[1][2*h+1]};
            float2v ex2 = {acc[2][2*h], acc[2][2*h+1]};
            float2v ey2 = {acc[3][2*h], acc[3][2*h+1]};
            float2v exy = {acc[4][2*h], acc[4][2*h+1]};
            float2v P  = mx * my;
            float2v U  = mx * mx + my * my + C1v;     // mus^2 sum + C1
            float2v n1 = 2.f * P + C1v;
            float2v n2 = 2.f * (exy - P) + C2v;
            float2v num = n1 * n2;
            float2v e1 = (ex2 + ey2) - U + K12;       // sgx+sgy+C2
            float2v den = U * e1;
            float2v r = {__builtin_amdgcn_rcpf(den.x),
                         __builtin_amdgcn_rcpf(den.y)};
            lsum2 += num * r;
        }
    }
    float lsum = lsum2.x + lsum2.y;

    #pragma unroll
    for (int off = 32; off > 0; off >>= 1)
        lsum += __shfl_down(lsum, off, 64);
    if (lane == 0) wred[w] = lsum;
    __syncthreads();
    if (t == 0) partial[bid] = wred[0] + wred[1] + wred[2] + wred[3];
}

// Single-block finish: 1024 threads x 6 loads, deterministic tree reduce.
__global__ __launch_bounds__(1024) void ssim_finish(
    const float* __restrict__ partial, float* __restrict__ out)
{
    __shared__ float wred[16];
    const int t = threadIdx.x;
    float s = 0.f;
    #pragma unroll
    for (int i = 0; i < NBLK / 1024; ++i)
        s += partial[t + i * 1024];
    #pragma unroll
    for (int off = 32; off > 0; off >>= 1)
        s += __shfl_down(s, off, 64);
    if ((t & 63) == 0) wred[t >> 6] = s;
    __syncthreads();
    if (t == 0) {
        float acc = 0.f;
        #pragma unroll
        for (int i = 0; i < 16; ++i) acc += wred[i];
        out[0] = 1.f - acc * (1.f / (float)((long long)NCH * IMG * IMG));
    }
}

extern "C" void kernel_launch(void* const* d_in, const int* in_sizes, int n_in,
                              void* d_out, int out_size, void* d_ws, size_t ws_size,
                              hipStream_t stream)
{
    const float* pred = (const float*)d_in[0];
    const float* tgt  = (const float*)d_in[1];
    float* out     = (float*)d_out;
    float* partial = (float*)d_ws;    // NBLK floats = 24 KB

    ssim_tile_kernel<<<NBLK, 256, 0, stream>>>(pred, tgt, partial);
    ssim_finish<<<1, 1024, 0, stream>>>(partial, out);
}